// Round 14
// baseline (98.426 us; speedup 1.0000x reference)
//
#include <hip/hip_runtime.h>
#include <hip/hip_bf16.h>
#include <cstdint>
#include <cstddef>

#define P_ 256
#define L_ 6
#define D_ 300
#define J_ 3072   // P*2*L
#define N_ 4096
#define H_ 256
#define C_ 5
#define KP 320    // K padded to multiple of 32
#define KSTEPS 10 // KP/32

#define SLS 0.62245933120185459f  // sigmoid(0.5)

typedef __attribute__((ext_vector_type(8))) short short8v;  // 8 bf16
typedef __attribute__((ext_vector_type(4))) short short4v;  // 4 bf16 (8B)
typedef __attribute__((ext_vector_type(4))) float f32x4;

__device__ __forceinline__ float sigmoidf_(float x) { return 1.0f / (1.0f + __expf(-x)); }
__device__ __forceinline__ float bf2f(short s) { return __uint_as_float(((unsigned)(unsigned short)s) << 16); }
__device__ __forceinline__ short f2bf(float f) {
    __hip_bfloat16 h = __float2bfloat16(f);
    return *reinterpret_cast<const short*>(&h);
}

// RMW poll: served at the coherence point (no stale per-XCD L2 line, no
// cache-wide invalidate). [R8-proven]
__device__ __forceinline__ int rmw_peek(int* p) {
    return __hip_atomic_fetch_add(p, 0, __ATOMIC_RELAXED, __HIP_MEMORY_SCOPE_AGENT);
}

// ---------------------------------------------------------------------------
// Kernel 1: gather emb[doc] -> X bf16 [N_][KP]; diags -> Bb bf16 [J_][KP].
// Vectorized float4 -> bf16x4. Also zeroes the 256 per-pattern flags
// (plain stores; kernel-boundary flush makes them visible — R11-proven).
// ---------------------------------------------------------------------------
__global__ __launch_bounds__(256) void prep_XB(
    const int* __restrict__ doc, const float* __restrict__ emb,
    const float* __restrict__ diags,
    __hip_bfloat16* __restrict__ X, __hip_bfloat16* __restrict__ Bb,
    int* __restrict__ flags)
{
    const int i = blockIdx.x * 256 + threadIdx.x;   // float4 index
    if (i < P_ * 16) flags[i] = 0;
    const int NX4 = N_ * (KP / 4);
    float4 v = {0.f, 0.f, 0.f, 0.f};
    if (i < NX4) {
        const int n = i / (KP / 4), k4 = i - n * (KP / 4);
        if (k4 < D_ / 4)
            v = ((const float4*)(emb + (size_t)doc[n] * D_))[k4];
        short4v pk = { f2bf(v.x), f2bf(v.y), f2bf(v.z), f2bf(v.w) };
        *(short4v*)(X + (size_t)i * 4) = pk;
    } else {
        const int ii = i - NX4;
        const int j = ii / (KP / 4), k4 = ii - j * (KP / 4);
        if (k4 < D_ / 4)
            v = ((const float4*)(diags + (size_t)j * D_))[k4];
        short4v pk = { f2bf(v.x), f2bf(v.y), f2bf(v.z), f2bf(v.w) };
        *(short4v*)(Bb + (size_t)ii * 4) = pk;
    }
}

// ---------------------------------------------------------------------------
// Kernel 2: Tt = sigmoid(X @ Bb^T + bias)^T -> bf16 Tt[J_][N_] (TRANSPOSED).
// R3/R10's validated 2-phase 128x128 MFMA core (byte-identical).
// ---------------------------------------------------------------------------
__global__ __launch_bounds__(256) void gemm_mfma(
    const __hip_bfloat16* __restrict__ X, const __hip_bfloat16* __restrict__ Bb,
    const float* __restrict__ bias, __hip_bfloat16* __restrict__ Tt)
{
    __shared__ __hip_bfloat16 As[2][128 * 32];
    __shared__ __hip_bfloat16 Bs[2][128 * 32];

    const int tid  = threadIdx.x;
    const int lane = tid & 63;
    const int w    = tid >> 6;          // wave 0..3
    const int wr   = w >> 1, wc = w & 1;

    // XCD-aware bijective swizzle: nwg = 768 = 8 * 96
    const int bid = blockIdx.x;
    const int swz = (bid & 7) * 96 + (bid >> 3);
    const int bx  = swz % 24, by = swz / 24;   // 24 j-tiles, 32 m-tiles
    const int m0  = by * 128;
    const int j0  = bx * 128;

    const int srow = w * 32 + (lane >> 2);   // + q*16
    const int scol = (lane & 3) * 8;

    f32x4 acc[4][4];
    #pragma unroll
    for (int m = 0; m < 4; ++m)
        #pragma unroll
        for (int n = 0; n < 4; ++n)
            acc[m][n] = (f32x4){0.f, 0.f, 0.f, 0.f};

    const int fr = lane & 15;
    const int kg = (lane >> 4) * 8;

    auto stage = [&](int kt, int b) {
        const int k0 = kt * 32;
        #pragma unroll
        for (int q = 0; q < 2; ++q) {
            const __hip_bfloat16* ga = X + (size_t)(m0 + srow + q * 16) * KP + k0 + scol;
            __builtin_amdgcn_global_load_lds(
                (const __attribute__((address_space(1))) unsigned*)ga,
                (__attribute__((address_space(3))) unsigned*)(&As[b][(w * 2 + q) * 512]),
                16, 0, 0);
            const __hip_bfloat16* gb = Bb + (size_t)(j0 + srow + q * 16) * KP + k0 + scol;
            __builtin_amdgcn_global_load_lds(
                (const __attribute__((address_space(1))) unsigned*)gb,
                (__attribute__((address_space(3))) unsigned*)(&Bs[b][(w * 2 + q) * 512]),
                16, 0, 0);
        }
    };

    stage(0, 0);
    __syncthreads();

    int buf = 0;
    for (int kt = 0; kt < KSTEPS; ++kt) {
        if (kt + 1 < KSTEPS) stage(kt + 1, buf ^ 1);

        short8v a[4], b[4];
        #pragma unroll
        for (int m = 0; m < 4; ++m)
            a[m] = *(const short8v*)(&As[buf][(wr * 64 + m * 16 + fr) * 32 + kg]);
        #pragma unroll
        for (int n = 0; n < 4; ++n)
            b[n] = *(const short8v*)(&Bs[buf][(wc * 64 + n * 16 + fr) * 32 + kg]);
        #pragma unroll
        for (int m = 0; m < 4; ++m)
            #pragma unroll
            for (int n = 0; n < 4; ++n)
                acc[m][n] = __builtin_amdgcn_mfma_f32_16x16x32_bf16(a[m], b[n], acc[m][n], 0, 0, 0);

        __syncthreads();
        buf ^= 1;
    }

    // epilogue: C/D mapping col=lane&15, row=(lane>>4)*4+reg  [m89-verified]
    #pragma unroll
    for (int n = 0; n < 4; ++n) {
        const int j = j0 + wc * 64 + n * 16 + fr;
        const float bj = bias[j];
        #pragma unroll
        for (int m = 0; m < 4; ++m) {
            const int rbase = m0 + wr * 64 + m * 16 + (lane >> 4) * 4;
            short4v pk;
            #pragma unroll
            for (int r = 0; r < 4; ++r)
                pk[r] = f2bf(sigmoidf_(acc[m][n][r] + bj));
            *(short4v*)(Tt + (size_t)j * N_ + rbase) = pk;
        }
    }
}

// ---------------------------------------------------------------------------
// Affine-map compose: N = C o R (apply R first, then C). Flat q = j*7+i.
// ---------------------------------------------------------------------------
__device__ __forceinline__ void compose_maps(const float* C, const float* R, float* N)
{
    #pragma unroll
    for (int j = 0; j < 7; ++j) {
        #pragma unroll
        for (int i = 0; i < 6; ++i) {
            float a = (j == 6) ? C[42 + i] : 0.0f;
            #pragma unroll
            for (int u = 0; u < 6; ++u) a = fmaf(C[u * 7 + i], R[j * 7 + u], a);
            N[j * 7 + i] = a;
        }
        float sa = R[j * 7 + 6] + ((j == 6) ? C[48] : 0.0f);
        #pragma unroll
        for (int u = 0; u < 6; ++u) sa = fmaf(C[u * 7 + 6], R[j * 7 + u], sa);
        N[j * 7 + 6] = sa;
    }
}

// ---------------------------------------------------------------------------
// Kernel 3 (grid 257): blocks 0..255 = per-pattern scan (unchanged logic);
// each ends with: plain score store -> fence -> atomic RELEASE store to its
// OWN flag line (no RMW contention, producers retire immediately).
// Block 256 = MLP: pre-warms 517KB weights into L3 while producers run, then
// each thread RMW-polls its own flag line, one acquire fence, runs the MLP.
// Deadlock-impossible: single waiter, producers never wait.
// ---------------------------------------------------------------------------
__global__ __launch_bounds__(256) void scan_mlp(
    const __hip_bfloat16* __restrict__ Tt, const float* __restrict__ epsilon,
    float* __restrict__ scores, int* __restrict__ flags,
    const float* __restrict__ w0, const float* __restrict__ b0,
    const float* __restrict__ w1, const float* __restrict__ b1,
    const float* __restrict__ w2, const float* __restrict__ b2,
    float* __restrict__ out)
{
    __shared__ float lds[256 * 49];   // 50176 B (scan); reused by MLP block
    const int tid = threadIdx.x;
    const int bid = blockIdx.x;

    if (bid < P_) {
        const int p = bid;
        // ---------------- P1: chunk map (thread = chunk c, 16 steps) -------
        {
            const int c = tid;
            float ep[5];
            #pragma unroll
            for (int l = 0; l < 5; ++l)
                ep[l] = SLS * (1.0f / (1.0f + __expf(-epsilon[p * 5 + l])));

            float hc[7][6], sc[7];
            #pragma unroll
            for (int j = 0; j < 7; ++j) {
                sc[j] = 0.0f;
                #pragma unroll
                for (int i = 0; i < 6; ++i) hc[j][i] = (i == j) ? 1.0f : 0.0f;
            }

            #pragma unroll
            for (int h = 0; h < 2; ++h) {
                short8v v[12];
                #pragma unroll
                for (int l = 0; l < 12; ++l)
                    v[l] = *(const short8v*)(Tt + (size_t)(p * 12 + l) * N_ + c * 16 + h * 8);

                #pragma unroll
                for (int tt = 0; tt < 8; ++tt) {
                    float sT0[6], T1v[6];
                    #pragma unroll
                    for (int l = 0; l < 6; ++l) {
                        sT0[l] = SLS * bf2f(v[l][tt]);
                        T1v[l] = bf2f(v[6 + l][tt]);
                    }
                    #pragma unroll
                    for (int j = 0; j < 7; ++j) {
                        float m[6];
                        m[0] = hc[j][0] * sT0[0];
                        #pragma unroll
                        for (int i = 1; i < 6; ++i)
                            m[i] = fmaf(hc[j][i - 1], T1v[i - 1], hc[j][i] * sT0[i]);
                        hc[j][0] = m[0] + ((j == 6) ? 1.0f : 0.0f);
                        #pragma unroll
                        for (int i = 1; i < 6; ++i)
                            hc[j][i] = fmaf(m[i - 1], ep[i - 1], m[i]);
                        sc[j] += hc[j][5];
                    }
                }
            }

            #pragma unroll
            for (int j = 0; j < 7; ++j) {
                #pragma unroll
                for (int i = 0; i < 6; ++i) lds[c * 49 + j * 7 + i] = hc[j][i];
                lds[c * 49 + j * 7 + 6] = sc[j];
            }
        }

        // ---------------- P2: in-LDS binary tree over 256 chunk maps -------
        for (int act = 128; act >= 1; act >>= 1) {
            __syncthreads();
            float Nn[49];
            const bool on = (tid < act);
            if (on) compose_maps(&lds[(2 * tid + 1) * 49], &lds[(2 * tid) * 49], Nn);
            __syncthreads();
            if (on) {
                #pragma unroll
                for (int q = 0; q < 49; ++q) lds[tid * 49 + q] = Nn[q];
            }
        }

        if (tid == 0) {
            scores[p] = lds[6] + lds[48];   // apply map to (h0=e0, s=0)
            __threadfence();                // release score to coherence point
            __hip_atomic_store(&flags[p * 16], 1, __ATOMIC_RELEASE,
                               __HIP_MEMORY_SCOPE_AGENT);
        }
        return;                             // producers retire immediately
    }

    // ======================= MLP block (bid == 256) ========================
    // Warm weights into L3 (memory-side cache; survives the acquire fence)
    // while the scan blocks run.
    {
        float acc = 0.f;
        for (int idx = tid; idx < (H_ * P_) / 4; idx += 256)
            { float4 v = ((const float4*)w0)[idx]; acc += v.x + v.y + v.z + v.w; }
        for (int idx = tid; idx < (H_ * H_) / 4; idx += 256)
            { float4 v = ((const float4*)w1)[idx]; acc += v.x + v.y + v.z + v.w; }
        for (int idx = tid; idx < (C_ * H_) / 4; idx += 256)
            { float4 v = ((const float4*)w2)[idx]; acc += v.x + v.y + v.z + v.w; }
        asm volatile("" :: "v"(acc));       // keep the warming loads live
    }

    // Each thread polls its own flag line (parallel, coherence-point RMW).
    {
        while (rmw_peek(&flags[tid * 16]) == 0) __builtin_amdgcn_s_sleep(4);
    }
    __syncthreads();
    if (tid == 0) __threadfence();          // one acquire: fresh scores view
    __syncthreads();

    // MLP (256 threads, R10-validated pattern), on L3-warm weights.
    {
        float* s0 = lds;
        float* z0 = lds + 256;
        float* z1 = lds + 512;

        s0[tid] = scores[tid];
        __syncthreads();

        float acc = b0[tid];
        {
            const float4* wr = (const float4*)(w0 + (size_t)tid * P_);
            #pragma unroll 4
            for (int q = 0; q < P_ / 4; ++q) {
                float4 w = wr[q];
                acc = fmaf(w.x, s0[q * 4 + 0], acc);
                acc = fmaf(w.y, s0[q * 4 + 1], acc);
                acc = fmaf(w.z, s0[q * 4 + 2], acc);
                acc = fmaf(w.w, s0[q * 4 + 3], acc);
            }
        }
        z0[tid] = fmaxf(acc, 0.0f);
        __syncthreads();

        acc = b1[tid];
        {
            const float4* wr = (const float4*)(w1 + (size_t)tid * H_);
            #pragma unroll 4
            for (int q = 0; q < H_ / 4; ++q) {
                float4 w = wr[q];
                acc = fmaf(w.x, z0[q * 4 + 0], acc);
                acc = fmaf(w.y, z0[q * 4 + 1], acc);
                acc = fmaf(w.z, z0[q * 4 + 2], acc);
                acc = fmaf(w.w, z0[q * 4 + 3], acc);
            }
        }
        z1[tid] = fmaxf(acc, 0.0f);
        __syncthreads();

        if (tid < C_) {
            float o = b2[tid];
            const float* wr = w2 + (size_t)tid * H_;
            for (int hh = 0; hh < H_; ++hh) o = fmaf(wr[hh], z1[hh], o);
            out[tid] = o;
        }
    }
}

// ---------------------------------------------------------------------------
extern "C" void kernel_launch(void* const* d_in, const int* in_sizes, int n_in,
                              void* d_out, int out_size, void* d_ws, size_t ws_size,
                              hipStream_t stream)
{
    const int*   doc     = (const int*)d_in[0];
    const float* emb     = (const float*)d_in[1];
    const float* diags   = (const float*)d_in[2];
    const float* bias    = (const float*)d_in[3];
    const float* epsilon = (const float*)d_in[4];
    const float* w0      = (const float*)d_in[5];
    const float* b0      = (const float*)d_in[6];
    const float* w1      = (const float*)d_in[7];
    const float* b1      = (const float*)d_in[8];
    const float* w2      = (const float*)d_in[9];
    const float* b2      = (const float*)d_in[10];
    float* out = (float*)d_out;

    // Workspace (~30 MB): scores (1 KB) + flags (16 KB), then bf16 arrays.
    float* scores = (float*)d_ws;                                 // 256 floats
    int*   flags  = (int*)(scores + P_);                          // 4096 ints
    __hip_bfloat16* Tt = (__hip_bfloat16*)((int*)flags + P_ * 16);// J_*N_ (25.2 MB)
    __hip_bfloat16* X  = Tt + (size_t)J_ * N_;                    // N_*KP ( 2.6 MB)
    __hip_bfloat16* Bb = X  + (size_t)N_ * KP;                    // J_*KP ( 2.0 MB)

    prep_XB<<<(N_ * KP + J_ * KP) / 1024, 256, 0, stream>>>(doc, emb, diags, X, Bb, flags);
    gemm_mfma<<<(J_ / 128) * (N_ / 128), 256, 0, stream>>>(X, Bb, bias, Tt);
    scan_mlp<<<P_ + 1, 256, 0, stream>>>(Tt, epsilon, scores, flags,
                                         w0, b0, w1, b1, w2, b2, out);
}

// Round 15
// 73.310 us; speedup vs baseline: 1.3426x; 1.3426x over previous
//
#include <hip/hip_runtime.h>
#include <hip/hip_bf16.h>
#include <cstdint>
#include <cstddef>

#define P_ 256
#define L_ 6
#define D_ 300
#define J_ 3072   // P*2*L
#define N_ 4096
#define H_ 256
#define C_ 5
#define KSTEPS 10 // 10*32 = 320 >= 300; tail step zero-padded in LDS

#define SLS 0.62245933120185459f  // sigmoid(0.5)

typedef __attribute__((ext_vector_type(8))) short short8v;  // 8 bf16
typedef __attribute__((ext_vector_type(4))) short short4v;  // 4 bf16 (8B)
typedef __attribute__((ext_vector_type(4))) float f32x4;

__device__ __forceinline__ float sigmoidf_(float x) { return 1.0f / (1.0f + __expf(-x)); }
__device__ __forceinline__ float bf2f(short s) { return __uint_as_float(((unsigned)(unsigned short)s) << 16); }
__device__ __forceinline__ short f2bf(float f) {
    __hip_bfloat16 h = __float2bfloat16(f);
    return *reinterpret_cast<const short*>(&h);
}

// ---------------------------------------------------------------------------
// Kernel 1 (prep ELIMINATED): Tt = sigmoid(emb[doc] @ diags^T + bias)^T
// -> bf16 Tt[J_][N_] (transposed).
// fp32 staged DIRECT from emb/diags via global_load_lds (per-lane source
// addressing does the doc-gather on the DMA path). LDS tiles are fp32 with a
// rule-21 XOR 16B-block swizzle applied on the SOURCE address (LDS dest
// linear) and on the ds_read side: slot s of row r holds global block
// s ^ (r&7) -> ds_read aliasing stays ~8-way (same as the bf16 layout).
// Fragments convert fp32->bf16 in-register with the SAME RNE cast prep used.
// K-tail (cols 300..319): lanes whose block is valid issue loads; others
// ds_write zeros (disjoint addresses, exec-masked, no race).
// ---------------------------------------------------------------------------
__global__ __launch_bounds__(256) void gemm_fp32d(
    const int* __restrict__ doc, const float* __restrict__ emb,
    const float* __restrict__ diags, const float* __restrict__ bias,
    __hip_bfloat16* __restrict__ Tt)
{
    __shared__ float As[2][4096];   // [128 rows][32 fp32], swizzled blocks
    __shared__ float Bs[2][4096];

    const int tid  = threadIdx.x;
    const int lane = tid & 63;
    const int w    = tid >> 6;          // wave 0..3
    const int wr   = w >> 1, wc = w & 1;

    // XCD-aware bijective swizzle: nwg = 768 = 8 * 96
    const int bid = blockIdx.x;
    const int swz = (bid & 7) * 96 + (bid >> 3);
    const int bx  = swz % 24, by = swz / 24;   // 24 j-tiles, 32 m-tiles
    const int m0  = by * 128;
    const int j0  = bx * 128;

    // staging geometry: issue q covers rows w*32+q*8 + (lane>>3),
    // dest slot lane&7; source block = slot ^ (row&7) = (lane&7)^(lane>>3).
    const int hrow = lane >> 3;              // 0..7
    const int sblk = (lane & 7) ^ hrow;      // swizzled global 16B block
    int rloc[4], drow[4];
    #pragma unroll
    for (int q = 0; q < 4; ++q) {
        rloc[q] = w * 32 + q * 8 + hrow;
        drow[q] = doc[m0 + rloc[q]];
    }

    auto stage = [&](int kt, int b) {
        const int k0 = kt * 32;
        const bool tail = (kt == KSTEPS - 1);
        #pragma unroll
        for (int q = 0; q < 4; ++q) {
            float* dstA = &As[b][w * 1024 + q * 256 + lane * 4];
            float* dstB = &Bs[b][w * 1024 + q * 256 + lane * 4];
            if (!tail || sblk < 3) {   // k0+sblk*4+4 <= 300 when sblk<=2
                const float* ga = emb + (size_t)drow[q] * D_ + k0 + sblk * 4;
                __builtin_amdgcn_global_load_lds(
                    (const __attribute__((address_space(1))) unsigned*)ga,
                    (__attribute__((address_space(3))) unsigned*)dstA, 16, 0, 0);
                const float* gb = diags + (size_t)(j0 + rloc[q]) * D_ + k0 + sblk * 4;
                __builtin_amdgcn_global_load_lds(
                    (const __attribute__((address_space(1))) unsigned*)gb,
                    (__attribute__((address_space(3))) unsigned*)dstB, 16, 0, 0);
            } else {
                *(f32x4*)dstA = (f32x4){0.f, 0.f, 0.f, 0.f};
                *(f32x4*)dstB = (f32x4){0.f, 0.f, 0.f, 0.f};
            }
        }
    };

    f32x4 acc[4][4];
    #pragma unroll
    for (int m = 0; m < 4; ++m)
        #pragma unroll
        for (int n = 0; n < 4; ++n)
            acc[m][n] = (f32x4){0.f, 0.f, 0.f, 0.f};

    const int fr = lane & 15;
    const int kq = lane >> 4;                    // 0..3 (k-group of 8 fp32)
    const int f7 = fr & 7;
    const int s0 = ((2 * kq)     ^ f7) * 4;      // float offset, low block
    const int s1 = ((2 * kq + 1) ^ f7) * 4;      // float offset, high block

    stage(0, 0);
    __syncthreads();

    int buf = 0;
    for (int kt = 0; kt < KSTEPS; ++kt) {
        if (kt + 1 < KSTEPS) stage(kt + 1, buf ^ 1);

        short8v a[4], b[4];
        #pragma unroll
        for (int m = 0; m < 4; ++m) {
            const int ra = (wr * 64 + m * 16 + fr) * 32;
            f32x4 lo = *(const f32x4*)(&As[buf][ra + s0]);
            f32x4 hi = *(const f32x4*)(&As[buf][ra + s1]);
            short8v v;
            #pragma unroll
            for (int e = 0; e < 4; ++e) { v[e] = f2bf(lo[e]); v[4 + e] = f2bf(hi[e]); }
            a[m] = v;
        }
        #pragma unroll
        for (int n = 0; n < 4; ++n) {
            const int rb = (wc * 64 + n * 16 + fr) * 32;
            f32x4 lo = *(const f32x4*)(&Bs[buf][rb + s0]);
            f32x4 hi = *(const f32x4*)(&Bs[buf][rb + s1]);
            short8v v;
            #pragma unroll
            for (int e = 0; e < 4; ++e) { v[e] = f2bf(lo[e]); v[4 + e] = f2bf(hi[e]); }
            b[n] = v;
        }
        #pragma unroll
        for (int m = 0; m < 4; ++m)
            #pragma unroll
            for (int n = 0; n < 4; ++n)
                acc[m][n] = __builtin_amdgcn_mfma_f32_16x16x32_bf16(a[m], b[n], acc[m][n], 0, 0, 0);

        __syncthreads();
        buf ^= 1;
    }

    // epilogue: C/D mapping col=lane&15, row=(lane>>4)*4+reg  [m89-verified]
    #pragma unroll
    for (int n = 0; n < 4; ++n) {
        const int j = j0 + wc * 64 + n * 16 + fr;
        const float bj = bias[j];
        #pragma unroll
        for (int m = 0; m < 4; ++m) {
            const int rbase = m0 + wr * 64 + m * 16 + (lane >> 4) * 4;
            short4v pk;
            #pragma unroll
            for (int r = 0; r < 4; ++r)
                pk[r] = f2bf(sigmoidf_(acc[m][n][r] + bj));
            *(short4v*)(Tt + (size_t)j * N_ + rbase) = pk;
        }
    }
}

// ---------------------------------------------------------------------------
// Affine-map compose: N = C o R (apply R first, then C). Flat q = j*7+i.
// ---------------------------------------------------------------------------
__device__ __forceinline__ void compose_maps(const float* C, const float* R, float* N)
{
    #pragma unroll
    for (int j = 0; j < 7; ++j) {
        #pragma unroll
        for (int i = 0; i < 6; ++i) {
            float a = (j == 6) ? C[42 + i] : 0.0f;
            #pragma unroll
            for (int u = 0; u < 6; ++u) a = fmaf(C[u * 7 + i], R[j * 7 + u], a);
            N[j * 7 + i] = a;
        }
        float sa = R[j * 7 + 6] + ((j == 6) ? C[48] : 0.0f);
        #pragma unroll
        for (int u = 0; u < 6; ++u) sa = fmaf(C[u * 7 + 6], R[j * 7 + u], sa);
        N[j * 7 + 6] = sa;
    }
}

// ---------------------------------------------------------------------------
// Kernel 2 (block = PATTERN, fully block-local — no cross-block sync):
//  P1: thread c computes chunk c's map (16 steps) from Tt (coalesced) -> LDS.
//  P2: in-LDS binary tree (8 levels) -> scores[p].  [R10/R13-validated]
// ---------------------------------------------------------------------------
__global__ __launch_bounds__(256) void scan_tree(
    const __hip_bfloat16* __restrict__ Tt, const float* __restrict__ epsilon,
    float* __restrict__ scores)
{
    __shared__ float lds[256 * 49];   // 50176 B
    const int tid = threadIdx.x;
    const int p   = blockIdx.x;       // pattern

    {
        const int c = tid;
        float ep[5];
        #pragma unroll
        for (int l = 0; l < 5; ++l)
            ep[l] = SLS * (1.0f / (1.0f + __expf(-epsilon[p * 5 + l])));

        float hc[7][6], sc[7];
        #pragma unroll
        for (int j = 0; j < 7; ++j) {
            sc[j] = 0.0f;
            #pragma unroll
            for (int i = 0; i < 6; ++i) hc[j][i] = (i == j) ? 1.0f : 0.0f;
        }

        #pragma unroll
        for (int h = 0; h < 2; ++h) {
            short8v v[12];
            #pragma unroll
            for (int l = 0; l < 12; ++l)
                v[l] = *(const short8v*)(Tt + (size_t)(p * 12 + l) * N_ + c * 16 + h * 8);

            #pragma unroll
            for (int tt = 0; tt < 8; ++tt) {
                float sT0[6], T1v[6];
                #pragma unroll
                for (int l = 0; l < 6; ++l) {
                    sT0[l] = SLS * bf2f(v[l][tt]);
                    T1v[l] = bf2f(v[6 + l][tt]);
                }
                #pragma unroll
                for (int j = 0; j < 7; ++j) {
                    float m[6];
                    m[0] = hc[j][0] * sT0[0];
                    #pragma unroll
                    for (int i = 1; i < 6; ++i)
                        m[i] = fmaf(hc[j][i - 1], T1v[i - 1], hc[j][i] * sT0[i]);
                    hc[j][0] = m[0] + ((j == 6) ? 1.0f : 0.0f);
                    #pragma unroll
                    for (int i = 1; i < 6; ++i)
                        hc[j][i] = fmaf(m[i - 1], ep[i - 1], m[i]);
                    sc[j] += hc[j][5];
                }
            }
        }

        #pragma unroll
        for (int j = 0; j < 7; ++j) {
            #pragma unroll
            for (int i = 0; i < 6; ++i) lds[c * 49 + j * 7 + i] = hc[j][i];
            lds[c * 49 + j * 7 + 6] = sc[j];
        }
    }

    for (int act = 128; act >= 1; act >>= 1) {
        __syncthreads();
        float Nn[49];
        const bool on = (tid < act);
        if (on) compose_maps(&lds[(2 * tid + 1) * 49], &lds[(2 * tid) * 49], Nn);
        __syncthreads();
        if (on) {
            #pragma unroll
            for (int q = 0; q < 49; ++q) lds[tid * 49 + q] = Nn[q];
        }
    }

    if (tid == 0) scores[p] = lds[6] + lds[48];
}

// ---------------------------------------------------------------------------
// Kernel 3: MLP head, 1024 threads (R13-validated: 4 partials/row + reduce).
// ---------------------------------------------------------------------------
__global__ __launch_bounds__(1024) void mlp_head(
    const float* __restrict__ scores,
    const float* __restrict__ w0, const float* __restrict__ b0,
    const float* __restrict__ w1, const float* __restrict__ b1,
    const float* __restrict__ w2, const float* __restrict__ b2,
    float* __restrict__ out)
{
    __shared__ float s0[H_], z0[H_], z1[H_];
    __shared__ float part[1024];
    const int tid = threadIdx.x;
    const int r = tid >> 2;          // row 0..255
    const int q = tid & 3;           // quarter 0..3

    if (tid < P_) s0[tid] = scores[tid];
    __syncthreads();

    {
        const float4* wr = (const float4*)(w0 + (size_t)r * P_ + q * 64);
        float sum = 0.f;
        #pragma unroll
        for (int k = 0; k < 16; ++k) {
            float4 wv = wr[k];
            const float* sv = &s0[q * 64 + k * 4];
            sum = fmaf(wv.x, sv[0], sum);
            sum = fmaf(wv.y, sv[1], sum);
            sum = fmaf(wv.z, sv[2], sum);
            sum = fmaf(wv.w, sv[3], sum);
        }
        part[tid] = sum;
    }
    __syncthreads();
    if (tid < H_) {
        float s = part[4 * tid] + part[4 * tid + 1] + part[4 * tid + 2] + part[4 * tid + 3];
        z0[tid] = fmaxf(s + b0[tid], 0.f);
    }
    __syncthreads();

    {
        const float4* wr = (const float4*)(w1 + (size_t)r * H_ + q * 64);
        float sum = 0.f;
        #pragma unroll
        for (int k = 0; k < 16; ++k) {
            float4 wv = wr[k];
            const float* sv = &z0[q * 64 + k * 4];
            sum = fmaf(wv.x, sv[0], sum);
            sum = fmaf(wv.y, sv[1], sum);
            sum = fmaf(wv.z, sv[2], sum);
            sum = fmaf(wv.w, sv[3], sum);
        }
        part[tid] = sum;
    }
    __syncthreads();
    if (tid < H_) {
        float s = part[4 * tid] + part[4 * tid + 1] + part[4 * tid + 2] + part[4 * tid + 3];
        z1[tid] = fmaxf(s + b1[tid], 0.f);
    }
    __syncthreads();

    if (tid < C_ * 64) {
        const int rr = tid >> 6, u = tid & 63;
        float4 wv = ((const float4*)(w2 + (size_t)rr * H_))[u];
        const float* sv = &z1[u * 4];
        float sum = wv.x * sv[0] + wv.y * sv[1] + wv.z * sv[2] + wv.w * sv[3];
        #pragma unroll
        for (int msk = 32; msk >= 1; msk >>= 1) sum += __shfl_xor(sum, msk, 64);
        if (u == 0) out[rr] = sum + b2[rr];
    }
}

// ---------------------------------------------------------------------------
extern "C" void kernel_launch(void* const* d_in, const int* in_sizes, int n_in,
                              void* d_out, int out_size, void* d_ws, size_t ws_size,
                              hipStream_t stream)
{
    const int*   doc     = (const int*)d_in[0];
    const float* emb     = (const float*)d_in[1];
    const float* diags   = (const float*)d_in[2];
    const float* bias    = (const float*)d_in[3];
    const float* epsilon = (const float*)d_in[4];
    const float* w0      = (const float*)d_in[5];
    const float* b0      = (const float*)d_in[6];
    const float* w1      = (const float*)d_in[7];
    const float* b1      = (const float*)d_in[8];
    const float* w2      = (const float*)d_in[9];
    const float* b2      = (const float*)d_in[10];
    float* out = (float*)d_out;

    // Workspace (~25.3 MB): scores (1 KB), then Tt bf16 (16B-aligned).
    float* scores = (float*)d_ws;                                // 256 floats
    __hip_bfloat16* Tt = (__hip_bfloat16*)((float*)d_ws + 512);  // J_*N_ (25.2 MB)

    gemm_fp32d<<<(J_ / 128) * (N_ / 128), 256, 0, stream>>>(doc, emb, diags, bias, Tt);
    scan_tree<<<P_, 256, 0, stream>>>(Tt, epsilon, scores);
    mlp_head<<<1, 1024, 0, stream>>>(scores, w0, b0, w1, b1, w2, b2, out);
}

// Round 16
// 63.964 us; speedup vs baseline: 1.5388x; 1.1461x over previous
//
#include <hip/hip_runtime.h>
#include <hip/hip_bf16.h>
#include <cstdint>
#include <cstddef>

#define P_ 256
#define L_ 6
#define D_ 300
#define J_ 3072   // P*2*L
#define N_ 4096
#define H_ 256
#define C_ 5
#define KP 320    // K padded to multiple of 32
#define KSTEPS 10 // KP/32

#define SLS 0.62245933120185459f  // sigmoid(0.5)

typedef __attribute__((ext_vector_type(8))) short short8v;  // 8 bf16
typedef __attribute__((ext_vector_type(4))) short short4v;  // 4 bf16 (8B)
typedef __attribute__((ext_vector_type(4))) float f32x4;

__device__ __forceinline__ float sigmoidf_(float x) { return 1.0f / (1.0f + __expf(-x)); }
__device__ __forceinline__ float bf2f(short s) { return __uint_as_float(((unsigned)(unsigned short)s) << 16); }
__device__ __forceinline__ short f2bf(float f) {
    __hip_bfloat16 h = __float2bfloat16(f);
    return *reinterpret_cast<const short*>(&h);
}

// ---------------------------------------------------------------------------
// Kernel 1: gather emb[doc] -> X bf16 [N_][KP]; diags -> Bb bf16 [J_][KP].
// Vectorized: 1 float4 (4 elems) per thread, 8B bf16x4 stores.
// Row pitch 300 floats = 1200 B (16B-aligned); 75 real float4 + 5 zero slots.
// [R13-validated]
// ---------------------------------------------------------------------------
__global__ __launch_bounds__(256) void prep_XB(
    const int* __restrict__ doc, const float* __restrict__ emb,
    const float* __restrict__ diags,
    __hip_bfloat16* __restrict__ X, __hip_bfloat16* __restrict__ Bb)
{
    const int i = blockIdx.x * 256 + threadIdx.x;   // float4 index
    const int NX4 = N_ * (KP / 4);
    float4 v = {0.f, 0.f, 0.f, 0.f};
    if (i < NX4) {
        const int n = i / (KP / 4), k4 = i - n * (KP / 4);
        if (k4 < D_ / 4)
            v = ((const float4*)(emb + (size_t)doc[n] * D_))[k4];
        short4v pk = { f2bf(v.x), f2bf(v.y), f2bf(v.z), f2bf(v.w) };
        *(short4v*)(X + (size_t)i * 4) = pk;
    } else {
        const int ii = i - NX4;
        const int j = ii / (KP / 4), k4 = ii - j * (KP / 4);
        if (k4 < D_ / 4)
            v = ((const float4*)(diags + (size_t)j * D_))[k4];
        short4v pk = { f2bf(v.x), f2bf(v.y), f2bf(v.z), f2bf(v.w) };
        *(short4v*)(Bb + (size_t)ii * 4) = pk;
    }
}

// ---------------------------------------------------------------------------
// Kernel 2: Tt = sigmoid(X @ Bb^T + bias)^T -> bf16 Tt[J_][N_] (TRANSPOSED).
// R3/R10/R13-validated 2-phase 128x128 MFMA core; epilogue packs the 4
// accumulator rows (consecutive timesteps, one column j) into one 8B store.
// 768 blocks = exactly 3/CU (even residency); bf16 operands keep the
// re-read staging traffic at ~127 MB L2-served (fp32-direct was 2x, R15 -9us).
// ---------------------------------------------------------------------------
__global__ __launch_bounds__(256) void gemm_mfma(
    const __hip_bfloat16* __restrict__ X, const __hip_bfloat16* __restrict__ Bb,
    const float* __restrict__ bias, __hip_bfloat16* __restrict__ Tt)
{
    __shared__ __hip_bfloat16 As[2][128 * 32];
    __shared__ __hip_bfloat16 Bs[2][128 * 32];

    const int tid  = threadIdx.x;
    const int lane = tid & 63;
    const int w    = tid >> 6;          // wave 0..3
    const int wr   = w >> 1, wc = w & 1;

    // XCD-aware bijective swizzle: nwg = 768 = 8 * 96
    const int bid = blockIdx.x;
    const int swz = (bid & 7) * 96 + (bid >> 3);
    const int bx  = swz % 24, by = swz / 24;   // 24 j-tiles, 32 m-tiles
    const int m0  = by * 128;
    const int j0  = bx * 128;

    const int srow = w * 32 + (lane >> 2);   // + q*16
    const int scol = (lane & 3) * 8;

    f32x4 acc[4][4];
    #pragma unroll
    for (int m = 0; m < 4; ++m)
        #pragma unroll
        for (int n = 0; n < 4; ++n)
            acc[m][n] = (f32x4){0.f, 0.f, 0.f, 0.f};

    const int fr = lane & 15;
    const int kg = (lane >> 4) * 8;

    auto stage = [&](int kt, int b) {
        const int k0 = kt * 32;
        #pragma unroll
        for (int q = 0; q < 2; ++q) {
            const __hip_bfloat16* ga = X + (size_t)(m0 + srow + q * 16) * KP + k0 + scol;
            __builtin_amdgcn_global_load_lds(
                (const __attribute__((address_space(1))) unsigned*)ga,
                (__attribute__((address_space(3))) unsigned*)(&As[b][(w * 2 + q) * 512]),
                16, 0, 0);
            const __hip_bfloat16* gb = Bb + (size_t)(j0 + srow + q * 16) * KP + k0 + scol;
            __builtin_amdgcn_global_load_lds(
                (const __attribute__((address_space(1))) unsigned*)gb,
                (__attribute__((address_space(3))) unsigned*)(&Bs[b][(w * 2 + q) * 512]),
                16, 0, 0);
        }
    };

    stage(0, 0);
    __syncthreads();

    int buf = 0;
    for (int kt = 0; kt < KSTEPS; ++kt) {
        if (kt + 1 < KSTEPS) stage(kt + 1, buf ^ 1);

        short8v a[4], b[4];
        #pragma unroll
        for (int m = 0; m < 4; ++m)
            a[m] = *(const short8v*)(&As[buf][(wr * 64 + m * 16 + fr) * 32 + kg]);
        #pragma unroll
        for (int n = 0; n < 4; ++n)
            b[n] = *(const short8v*)(&Bs[buf][(wc * 64 + n * 16 + fr) * 32 + kg]);
        #pragma unroll
        for (int m = 0; m < 4; ++m)
            #pragma unroll
            for (int n = 0; n < 4; ++n)
                acc[m][n] = __builtin_amdgcn_mfma_f32_16x16x32_bf16(a[m], b[n], acc[m][n], 0, 0, 0);

        __syncthreads();
        buf ^= 1;
    }

    // epilogue: C/D mapping col=lane&15, row=(lane>>4)*4+reg  [m89-verified]
    #pragma unroll
    for (int n = 0; n < 4; ++n) {
        const int j = j0 + wc * 64 + n * 16 + fr;
        const float bj = bias[j];
        #pragma unroll
        for (int m = 0; m < 4; ++m) {
            const int rbase = m0 + wr * 64 + m * 16 + (lane >> 4) * 4;
            short4v pk;
            #pragma unroll
            for (int r = 0; r < 4; ++r)
                pk[r] = f2bf(sigmoidf_(acc[m][n][r] + bj));
            *(short4v*)(Tt + (size_t)j * N_ + rbase) = pk;
        }
    }
}

// ---------------------------------------------------------------------------
// Affine-map compose: N = C o R (apply R first, then C). Flat q = j*7+i.
// ---------------------------------------------------------------------------
__device__ __forceinline__ void compose_maps(const float* C, const float* R, float* N)
{
    #pragma unroll
    for (int j = 0; j < 7; ++j) {
        #pragma unroll
        for (int i = 0; i < 6; ++i) {
            float a = (j == 6) ? C[42 + i] : 0.0f;
            #pragma unroll
            for (int u = 0; u < 6; ++u) a = fmaf(C[u * 7 + i], R[j * 7 + u], a);
            N[j * 7 + i] = a;
        }
        float sa = R[j * 7 + 6] + ((j == 6) ? C[48] : 0.0f);
        #pragma unroll
        for (int u = 0; u < 6; ++u) sa = fmaf(C[u * 7 + 6], R[j * 7 + u], sa);
        N[j * 7 + 6] = sa;
    }
}

// ---------------------------------------------------------------------------
// Kernel 3 (block = PATTERN, fully block-local — no cross-block sync):
//  P1: thread c computes chunk c's map (16 steps) from Tt (coalesced) -> LDS.
//  P2: in-LDS binary tree (8 levels) -> scores[p].  [R10/R13-validated]
// ---------------------------------------------------------------------------
__global__ __launch_bounds__(256) void scan_tree(
    const __hip_bfloat16* __restrict__ Tt, const float* __restrict__ epsilon,
    float* __restrict__ scores)
{
    __shared__ float lds[256 * 49];   // 50176 B
    const int tid = threadIdx.x;
    const int p   = blockIdx.x;       // pattern

    {
        const int c = tid;
        float ep[5];
        #pragma unroll
        for (int l = 0; l < 5; ++l)
            ep[l] = SLS * (1.0f / (1.0f + __expf(-epsilon[p * 5 + l])));

        float hc[7][6], sc[7];
        #pragma unroll
        for (int j = 0; j < 7; ++j) {
            sc[j] = 0.0f;
            #pragma unroll
            for (int i = 0; i < 6; ++i) hc[j][i] = (i == j) ? 1.0f : 0.0f;
        }

        #pragma unroll
        for (int h = 0; h < 2; ++h) {
            short8v v[12];
            #pragma unroll
            for (int l = 0; l < 12; ++l)
                v[l] = *(const short8v*)(Tt + (size_t)(p * 12 + l) * N_ + c * 16 + h * 8);

            #pragma unroll
            for (int tt = 0; tt < 8; ++tt) {
                float sT0[6], T1v[6];
                #pragma unroll
                for (int l = 0; l < 6; ++l) {
                    sT0[l] = SLS * bf2f(v[l][tt]);
                    T1v[l] = bf2f(v[6 + l][tt]);
                }
                #pragma unroll
                for (int j = 0; j < 7; ++j) {
                    float m[6];
                    m[0] = hc[j][0] * sT0[0];
                    #pragma unroll
                    for (int i = 1; i < 6; ++i)
                        m[i] = fmaf(hc[j][i - 1], T1v[i - 1], hc[j][i] * sT0[i]);
                    hc[j][0] = m[0] + ((j == 6) ? 1.0f : 0.0f);
                    #pragma unroll
                    for (int i = 1; i < 6; ++i)
                        hc[j][i] = fmaf(m[i - 1], ep[i - 1], m[i]);
                    sc[j] += hc[j][5];
                }
            }
        }

        #pragma unroll
        for (int j = 0; j < 7; ++j) {
            #pragma unroll
            for (int i = 0; i < 6; ++i) lds[c * 49 + j * 7 + i] = hc[j][i];
            lds[c * 49 + j * 7 + 6] = sc[j];
        }
    }

    for (int act = 128; act >= 1; act >>= 1) {
        __syncthreads();
        float Nn[49];
        const bool on = (tid < act);
        if (on) compose_maps(&lds[(2 * tid + 1) * 49], &lds[(2 * tid) * 49], Nn);
        __syncthreads();
        if (on) {
            #pragma unroll
            for (int q = 0; q < 49; ++q) lds[tid * 49 + q] = Nn[q];
        }
    }

    // apply final map to (h0=e0, s=0): score = col0.s + col6.s
    if (tid == 0) scores[p] = lds[6] + lds[48];
}

// ---------------------------------------------------------------------------
// Kernel 4: MLP head, 1024 threads (R13-validated: 4 partials/row + reduce,
// 4x load concurrency on the 517KB weight stream).
// ---------------------------------------------------------------------------
__global__ __launch_bounds__(1024) void mlp_head(
    const float* __restrict__ scores,
    const float* __restrict__ w0, const float* __restrict__ b0,
    const float* __restrict__ w1, const float* __restrict__ b1,
    const float* __restrict__ w2, const float* __restrict__ b2,
    float* __restrict__ out)
{
    __shared__ float s0[H_], z0[H_], z1[H_];
    __shared__ float part[1024];
    const int tid = threadIdx.x;
    const int r = tid >> 2;          // row 0..255
    const int q = tid & 3;           // quarter 0..3

    if (tid < P_) s0[tid] = scores[tid];
    __syncthreads();

    {
        const float4* wr = (const float4*)(w0 + (size_t)r * P_ + q * 64);
        float sum = 0.f;
        #pragma unroll
        for (int k = 0; k < 16; ++k) {
            float4 wv = wr[k];
            const float* sv = &s0[q * 64 + k * 4];
            sum = fmaf(wv.x, sv[0], sum);
            sum = fmaf(wv.y, sv[1], sum);
            sum = fmaf(wv.z, sv[2], sum);
            sum = fmaf(wv.w, sv[3], sum);
        }
        part[tid] = sum;
    }
    __syncthreads();
    if (tid < H_) {
        float s = part[4 * tid] + part[4 * tid + 1] + part[4 * tid + 2] + part[4 * tid + 3];
        z0[tid] = fmaxf(s + b0[tid], 0.f);
    }
    __syncthreads();

    {
        const float4* wr = (const float4*)(w1 + (size_t)r * H_ + q * 64);
        float sum = 0.f;
        #pragma unroll
        for (int k = 0; k < 16; ++k) {
            float4 wv = wr[k];
            const float* sv = &z0[q * 64 + k * 4];
            sum = fmaf(wv.x, sv[0], sum);
            sum = fmaf(wv.y, sv[1], sum);
            sum = fmaf(wv.z, sv[2], sum);
            sum = fmaf(wv.w, sv[3], sum);
        }
        part[tid] = sum;
    }
    __syncthreads();
    if (tid < H_) {
        float s = part[4 * tid] + part[4 * tid + 1] + part[4 * tid + 2] + part[4 * tid + 3];
        z1[tid] = fmaxf(s + b1[tid], 0.f);
    }
    __syncthreads();

    if (tid < C_ * 64) {
        const int rr = tid >> 6, u = tid & 63;
        float4 wv = ((const float4*)(w2 + (size_t)rr * H_))[u];
        const float* sv = &z1[u * 4];
        float sum = wv.x * sv[0] + wv.y * sv[1] + wv.z * sv[2] + wv.w * sv[3];
        #pragma unroll
        for (int msk = 32; msk >= 1; msk >>= 1) sum += __shfl_xor(sum, msk, 64);
        if (u == 0) out[rr] = sum + b2[rr];
    }
}

// ---------------------------------------------------------------------------
extern "C" void kernel_launch(void* const* d_in, const int* in_sizes, int n_in,
                              void* d_out, int out_size, void* d_ws, size_t ws_size,
                              hipStream_t stream)
{
    const int*   doc     = (const int*)d_in[0];
    const float* emb     = (const float*)d_in[1];
    const float* diags   = (const float*)d_in[2];
    const float* bias    = (const float*)d_in[3];
    const float* epsilon = (const float*)d_in[4];
    const float* w0      = (const float*)d_in[5];
    const float* b0      = (const float*)d_in[6];
    const float* w1      = (const float*)d_in[7];
    const float* b1      = (const float*)d_in[8];
    const float* w2      = (const float*)d_in[9];
    const float* b2      = (const float*)d_in[10];
    float* out = (float*)d_out;

    // Workspace (~30 MB): scores (1 KB), then bf16 arrays (16B-aligned).
    float* scores = (float*)d_ws;                                // 256 floats
    __hip_bfloat16* Tt = (__hip_bfloat16*)((float*)d_ws + 512);  // J_*N_ (25.2 MB)
    __hip_bfloat16* X  = Tt + (size_t)J_ * N_;                   // N_*KP ( 2.6 MB)
    __hip_bfloat16* Bb = X  + (size_t)N_ * KP;                   // J_*KP ( 2.0 MB)

    prep_XB<<<(N_ * KP + J_ * KP) / 1024, 256, 0, stream>>>(doc, emb, diags, X, Bb);
    gemm_mfma<<<(J_ / 128) * (N_ / 128), 256, 0, stream>>>(X, Bb, bias, Tt);
    scan_tree<<<P_, 256, 0, stream>>>(Tt, epsilon, scores);
    mlp_head<<<1, 1024, 0, stream>>>(scores, w0, b0, w1, b1, w2, b2, out);
}